// Round 1
// 951.509 us; speedup vs baseline: 1.1408x; 1.1408x over previous
//
#include <hip/hip_runtime.h>
#include <math.h>

#define NE 64            // experts
#define TPB 64           // tokens per block (kernel 1)
#define KC 64            // K chunk
#define HDIM 4096
#define SEQ 4096
#define NTOK 32768       // B*S
#define CAP 128          // expert capacity
#define LS 68            // LDS row stride in floats (16B-aligned float4 rows, 2-way banks)
#define AMB_TH 2.0e-3f   // ambiguity threshold on fp32 logit gaps (fp32 err <= ~3e-4 worst)

// ---------------------------------------------------------------------------
// Kernel 1: logits GEMM (fp32 accumulate) + softmax + top3 + loss partials
//           + zero dispatch/combine + ambiguity flagging for fp64 fixup.
// grid = 512 blocks (64 tokens each), 256 threads -> 2 blocks/CU, 2 waves/SIMD
// ---------------------------------------------------------------------------
__global__ __launch_bounds__(256) void k_router(
    const float* __restrict__ hs, const float* __restrict__ rw,
    float* __restrict__ dispatch, float* __restrict__ combine,
    float* __restrict__ probs_out,
    int* __restrict__ idx_buf, float* __restrict__ wgt_buf,
    float* __restrict__ partials,
    int* __restrict__ fix_cnt, int* __restrict__ fix_list)
{
    __shared__ float shh[KC * LS];   // [k][token]; reused as logits [token][LS]
    __shared__ float sww[KC * LS];   // [k][expert]
    __shared__ float red1[4], red2[4];

    const int tid = threadIdx.x;
    const int tokBase = blockIdx.x * TPB;

    const int eg = tid & 15;         // experts 4*eg..4*eg+3
    const int tg = tid >> 4;         // tokens  4*tg..4*tg+3

    float acc[4][4];
#pragma unroll
    for (int i = 0; i < 4; ++i)
#pragma unroll
        for (int j = 0; j < 4; ++j) acc[i][j] = 0.f;

    // staging assignment: lane = row (token / expert), wave = quarter of KC
    const int r_ld  = tid & 63;
    const int k_off = (tid >> 6) * 16;
    const float* hrow = hs + (size_t)(tokBase + r_ld) * HDIM + k_off;
    const float* wrow = rw + (size_t)r_ld * HDIM + k_off;

    float4 hreg[4], wreg[4];
#pragma unroll
    for (int i = 0; i < 4; ++i) hreg[i] = *(const float4*)(hrow + i * 4);
#pragma unroll
    for (int i = 0; i < 4; ++i) wreg[i] = *(const float4*)(wrow + i * 4);

    const int nChunks = HDIM / KC;   // 64
    for (int c = 0; c < nChunks; ++c) {
        __syncthreads();
        // staged regs -> LDS transposed to [k][row]; banks: (4k + r)&31 -> 2-way (free)
#pragma unroll
        for (int i = 0; i < 4; ++i) {
            const int kk = k_off + i * 4;
            shh[(kk + 0) * LS + r_ld] = hreg[i].x;
            shh[(kk + 1) * LS + r_ld] = hreg[i].y;
            shh[(kk + 2) * LS + r_ld] = hreg[i].z;
            shh[(kk + 3) * LS + r_ld] = hreg[i].w;
            sww[(kk + 0) * LS + r_ld] = wreg[i].x;
            sww[(kk + 1) * LS + r_ld] = wreg[i].y;
            sww[(kk + 2) * LS + r_ld] = wreg[i].z;
            sww[(kk + 3) * LS + r_ld] = wreg[i].w;
        }
        __syncthreads();
        // prefetch next chunk while computing this one
        if (c + 1 < nChunks) {
            const float* hp = hrow + (size_t)(c + 1) * KC;
            const float* wp = wrow + (size_t)(c + 1) * KC;
#pragma unroll
            for (int i = 0; i < 4; ++i) hreg[i] = *(const float4*)(hp + i * 4);
#pragma unroll
            for (int i = 0; i < 4; ++i) wreg[i] = *(const float4*)(wp + i * 4);
        }
#pragma unroll 8
        for (int k = 0; k < KC; ++k) {
            const float4 h = *(const float4*)&shh[k * LS + 4 * tg];
            const float4 w = *(const float4*)&sww[k * LS + 4 * eg];
            const float hv[4] = {h.x, h.y, h.z, h.w};
            const float wv[4] = {w.x, w.y, w.z, w.w};
#pragma unroll
            for (int i = 0; i < 4; ++i)
#pragma unroll
                for (int j = 0; j < 4; ++j)
                    acc[i][j] = fmaf(hv[i], wv[j], acc[i][j]);
        }
    }

    // dump fp32 logits to LDS [token][LS] (reuse shh)
    __syncthreads();
#pragma unroll
    for (int i = 0; i < 4; ++i)
#pragma unroll
        for (int j = 0; j < 4; ++j)
            shh[(4 * tg + i) * LS + 4 * eg + j] = acc[i][j];
    __syncthreads();

    // zero dispatch & combine for this block's tokens (d_out is poisoned)
    {
        const float4 z4 = make_float4(0.f, 0.f, 0.f, 0.f);
        float4* dp = (float4*)(dispatch + (size_t)tokBase * NE);
        float4* cp = (float4*)(combine + (size_t)tokBase * NE);
#pragma unroll
        for (int m = 0; m < 4; ++m) {
            dp[m * 256 + tid] = z4;
            cp[m * 256 + tid] = z4;
        }
    }

    float p2 = 0.f, zl = 0.f;
    if (tid < TPB) {
        const float* rowl = &shh[tid * LS];

        // pass A: top-3 logits (strict > => lowest index wins ties, matching lax.top_k)
        float b0 = -3.4e38f, b1 = -3.4e38f, b2 = -3.4e38f;
        int i0 = 0, i1 = 0;
#pragma unroll
        for (int e = 0; e < NE; ++e) {
            const float l = rowl[e];
            if (l > b0)      { b2 = b1; b1 = b0; i1 = i0; b0 = l; i0 = e; }
            else if (l > b1) { b2 = b1; b1 = l; i1 = e; }
            else if (l > b2) { b2 = l; }
        }

        // pass B: softmax (mx == b0) + probs + loss partials
        float fp[NE];
        float sum = 0.f;
#pragma unroll
        for (int e = 0; e < NE; ++e) {
            const float s = expf(rowl[e] - b0);
            sum += s;
            fp[e] = s;
        }
        const float inv = 1.f / sum;
        float p2l = 0.f;
#pragma unroll
        for (int e = 0; e < NE; ++e) {
            const float p = fp[e] * inv;
            fp[e] = p;
            p2l += p * p;
        }
        float4* gp = (float4*)(probs_out + (size_t)(tokBase + tid) * NE);
#pragma unroll
        for (int q = 0; q < 16; ++q) gp[q] = *(float4*)&fp[4 * q];

        p2 = p2l;
        const float lse = b0 + logf(sum);
        zl = lse * lse;

        // renormalized top-2 weights: w0 = 1/(1+exp(l1-l0))
        const float w0 = 1.f / (1.f + expf(b1 - b0));
        const float w1 = 1.f / (1.f + expf(b0 - b1));
        idx_buf[(size_t)(tokBase + tid) * 2 + 0] = i0;
        idx_buf[(size_t)(tokBase + tid) * 2 + 1] = i1;
        wgt_buf[(size_t)(tokBase + tid) * 2 + 0] = w0;
        wgt_buf[(size_t)(tokBase + tid) * 2 + 1] = w1;

        // flag tokens whose ranking decisions are within fp32 GEMM error of a tie
        if ((b0 - b1 < AMB_TH) || (b1 - b2 < AMB_TH)) {
            const int p = atomicAdd(fix_cnt, 1);
            fix_list[p] = tokBase + tid;
        }
    }

    // block-reduce loss partials (deterministic; waves 1-3 contribute zeros)
#pragma unroll
    for (int off = 32; off; off >>= 1) {
        p2 += __shfl_down(p2, off);
        zl += __shfl_down(zl, off);
    }
    const int lane = tid & 63, wid = tid >> 6;
    if (lane == 0) { red1[wid] = p2; red2[wid] = zl; }
    __syncthreads();
    if (tid == 0) {
        partials[blockIdx.x * 2 + 0] = red1[0] + red1[1] + red1[2] + red1[3];
        partials[blockIdx.x * 2 + 1] = red2[0] + red2[1] + red2[2] + red2[3];
    }
}

// ---------------------------------------------------------------------------
// Kernel 1b: fp64 fixup of ambiguous tokens. One token per block-iteration;
// thread (e = tid&63, kq = tid>>6) accumulates a 1024-long fp64 partial dot.
// Overwrites idx_buf/wgt_buf so decisions match the all-fp64 kernel exactly.
// ---------------------------------------------------------------------------
__global__ __launch_bounds__(256) void k_fixup(
    const float* __restrict__ hs, const float* __restrict__ rw,
    const int* __restrict__ fix_cnt, const int* __restrict__ fix_list,
    int* __restrict__ idx_buf, float* __restrict__ wgt_buf)
{
    __shared__ double part[NE][5];
    __shared__ double lg[NE];
    const int tid = threadIdx.x;
    const int e  = tid & 63;
    const int kq = tid >> 6;           // quarter of HDIM
    const int n = fix_cnt[0];

    for (int fi = blockIdx.x; fi < n; fi += gridDim.x) {
        const int t = fix_list[fi];
        const float4* hp = (const float4*)(hs + (size_t)t * HDIM + kq * 1024);
        const float4* wp = (const float4*)(rw + (size_t)e * HDIM + kq * 1024);
        double a = 0.0;
#pragma unroll 4
        for (int i = 0; i < 256; ++i) {
            const float4 h = hp[i];
            const float4 w = wp[i];
            a = fma((double)h.x, (double)w.x, a);
            a = fma((double)h.y, (double)w.y, a);
            a = fma((double)h.z, (double)w.z, a);
            a = fma((double)h.w, (double)w.w, a);
        }
        part[e][kq] = a;
        __syncthreads();
        if (tid < NE)
            lg[tid] = part[tid][0] + part[tid][1] + part[tid][2] + part[tid][3];
        __syncthreads();
        if (tid == 0) {
            double b0 = -1.0e300, b1 = -1.0e300;
            int i0 = 0, i1 = 0;
            for (int x = 0; x < NE; ++x) {
                const double l = lg[x];
                if (l > b0)      { b1 = b0; i1 = i0; b0 = l; i0 = x; }
                else if (l > b1) { b1 = l; i1 = x; }
            }
            const double w0 = 1.0 / (1.0 + exp(b1 - b0));
            const double w1 = 1.0 / (1.0 + exp(b0 - b1));
            idx_buf[(size_t)t * 2 + 0] = i0;
            idx_buf[(size_t)t * 2 + 1] = i1;
            wgt_buf[(size_t)t * 2 + 0] = (float)w0;
            wgt_buf[(size_t)t * 2 + 1] = (float)w1;
        }
        __syncthreads();
    }
}

// ---------------------------------------------------------------------------
// Kernel 2: capacity-limited dispatch. One block per (batch, expert).
// Scans the 8192 k-major assignments of the batch in order, exact exclusive
// cumsum via ballot prefix + wave-count scan.
// ---------------------------------------------------------------------------
__global__ __launch_bounds__(256) void k_dispatch(
    const int* __restrict__ idx_buf, const float* __restrict__ wgt_buf,
    float* __restrict__ dispatch, float* __restrict__ combine)
{
    const int e = blockIdx.x & 63;
    const int b = blockIdx.x >> 6;
    __shared__ int wc[4];
    const int tid = threadIdx.x;
    const int lane = tid & 63, wid = tid >> 6;
    const int base = b * SEQ;

    int running = 0;
    for (int chunk = 0; chunk < 32; ++chunk) {
        int j = chunk * 256 + tid;         // k-major order: j = k*SEQ + s
        int k = j >> 12;
        int s = j & (SEQ - 1);
        int my = idx_buf[(size_t)(base + s) * 2 + k];
        bool m = (my == e);
        unsigned long long bal = __ballot(m);
        int prefix = __popcll(bal & ((1ull << lane) - 1ull));
        if (lane == 0) wc[wid] = __popcll(bal);
        __syncthreads();
        int woff = 0, tot = 0;
#pragma unroll
        for (int w = 0; w < 4; ++w) {
            int c = wc[w];
            tot += c;
            if (w < wid) woff += c;
        }
        if (m) {
            int pos = running + woff + prefix;
            if (pos < CAP) {
                size_t o = (size_t)(base + s) * NE + e;
                dispatch[o] = 1.0f;
                combine[o] = wgt_buf[(size_t)(base + s) * 2 + k];
            }
        }
        running += tot;
        __syncthreads();
    }
}

// ---------------------------------------------------------------------------
// Kernel 3: deterministic final reduce of 512 loss partials
// ---------------------------------------------------------------------------
__global__ __launch_bounds__(256) void k_final(
    const float* __restrict__ partials, float* __restrict__ out)
{
    __shared__ float r1[4], r2[4];
    const int tid = threadIdx.x;
    float a = partials[tid * 2 + 0] + partials[(tid + 256) * 2 + 0];
    float b = partials[tid * 2 + 1] + partials[(tid + 256) * 2 + 1];
#pragma unroll
    for (int off = 32; off; off >>= 1) {
        a += __shfl_down(a, off);
        b += __shfl_down(b, off);
    }
    const int lane = tid & 63, wid = tid >> 6;
    if (lane == 0) { r1[wid] = a; r2[wid] = b; }
    __syncthreads();
    if (tid == 0) {
        float at = r1[0] + r1[1] + r1[2] + r1[3];
        float bt = r2[0] + r2[1] + r2[2] + r2[3];
        out[0] = at / (float)NTOK * (float)NE;   // aux_loss
        out[1] = bt / (float)NTOK;               // z_loss
    }
}

extern "C" void kernel_launch(void* const* d_in, const int* in_sizes, int n_in,
                              void* d_out, int out_size, void* d_ws, size_t ws_size,
                              hipStream_t stream)
{
    const float* hs = (const float*)d_in[0];   // [8,4096,4096]
    const float* rw = (const float*)d_in[1];   // [64,4096]
    float* out = (float*)d_out;
    float* dispatch = out;                     // [B,S,E] = 2097152
    float* combine  = out + 2097152;
    float* probs    = out + 2 * 2097152;
    float* scalars  = out + 3 * 2097152;       // aux, z

    int*   idx_buf  = (int*)d_ws;                                 // 65536 ints
    float* wgt_buf  = (float*)((char*)d_ws + 65536 * 4);          // 65536 floats
    float* partials = (float*)((char*)d_ws + 65536 * 8);          // 1024 floats
    int*   fix_cnt  = (int*)((char*)d_ws + 65536 * 8 + 4096);     // 1 int
    int*   fix_list = (int*)((char*)d_ws + 65536 * 8 + 8192);     // <=32768 ints

    hipMemsetAsync(fix_cnt, 0, sizeof(int), stream);
    hipLaunchKernelGGL(k_router, dim3(NTOK / TPB), dim3(256), 0, stream,
                       hs, rw, dispatch, combine, probs, idx_buf, wgt_buf,
                       partials, fix_cnt, fix_list);
    hipLaunchKernelGGL(k_fixup, dim3(256), dim3(256), 0, stream,
                       hs, rw, fix_cnt, fix_list, idx_buf, wgt_buf);
    hipLaunchKernelGGL(k_dispatch, dim3(8 * NE), dim3(256), 0, stream,
                       idx_buf, wgt_buf, dispatch, combine);
    hipLaunchKernelGGL(k_final, dim3(1), dim3(256), 0, stream,
                       partials, scalars);
}